// Round 6
// baseline (136.137 us; speedup 1.0000x reference)
//
#include <hip/hip_runtime.h>
#include <stdint.h>

// ---------------------------------------------------------------------------
// Per-type MLP dispatch (ElemwiseModels): out[n] = MLP_{elems[n]}(desc[n])
//   L1: h1 = tanh(x @ W1[t] + b1[t])     x:256 -> 256
//   L2: h2 = tanh(h1 @ W2[t] + b2[t])    256 -> 256
//   L3: out = h2 . W3[t] + b3[t]         256 -> 1
// Strategy: counting-sort partition by type; 64-atom tiles; bf16 MFMA.
// x keeps a bf16 hi/lo split (staged in two 128-dim K-chunks, 32 KB buffer);
// h1 is plain bf16 (reuses the same 32 KB) -> ~35 KB LDS -> 4 blocks/CU.
// ---------------------------------------------------------------------------

typedef __attribute__((ext_vector_type(8))) short short8;   // 8 x bf16 frag
typedef __attribute__((ext_vector_type(4))) float f32x4;    // MFMA acc

#define NPB 256          // partition blocks
#define NTY 4            // types

__device__ __forceinline__ unsigned short f2bf(float f) {
    union { float f; uint32_t u; } v; v.f = f;
    uint32_t u = v.u;
    uint32_t r = (u + 0x7FFFu + ((u >> 16) & 1u)) >> 16;   // RN-even
    return (unsigned short)r;
}
__device__ __forceinline__ float bf2f(unsigned short h) {
    union { uint32_t u; float f; } v; v.u = ((uint32_t)h) << 16;
    return v.f;
}
__device__ __forceinline__ float fast_tanh(float x) {
    x = fminf(fmaxf(x, -10.0f), 10.0f);
    float e = __expf(2.0f * x);
    return (e - 1.0f) * __builtin_amdgcn_rcpf(e + 1.0f);
}

// ---------------- ws layout -------------------------------------------------
// hdr   (32 ints @ 0):      [0..3] counts, [8..11] base, [12..15] tilebase, [16] total tiles
// counts(4*NPB ints @128):  counts[t*NPB + b]
// cursor(4*NPB ints):       cursor[t*NPB + b]
// sorted(n ints)
// w1s / w2s (bf16) after sorted
// ---------------------------------------------------------------------------

__global__ void count_k(const int* __restrict__ elems, int n, int chunk,
                        int* __restrict__ counts) {
    __shared__ int h[NTY];
    if (threadIdx.x < NTY) h[threadIdx.x] = 0;
    __syncthreads();
    const int start = blockIdx.x * chunk;
    const int end   = min(start + chunk, n);
    for (int i = start + threadIdx.x; i < end; i += blockDim.x)
        atomicAdd(&h[elems[i]], 1);
    __syncthreads();
    if (threadIdx.x < NTY) counts[threadIdx.x * NPB + blockIdx.x] = h[threadIdx.x];
}

__global__ void prefix_k(const int* __restrict__ counts,
                         int* __restrict__ cursor, int* __restrict__ hdr) {
    __shared__ int tot[NTY];
    const int t = threadIdx.x;
    if (t < NTY) {
        int s = 0;
        for (int b = 0; b < NPB; ++b) s += counts[t * NPB + b];
        tot[t] = s;
    }
    __syncthreads();
    if (t == 0) {
        int b = 0, tb = 0;
        for (int ty = 0; ty < NTY; ++ty) {
            hdr[ty]      = tot[ty];
            hdr[8 + ty]  = b;
            hdr[12 + ty] = tb;
            b  += tot[ty];
            tb += (tot[ty] + 63) >> 6;
        }
        hdr[16] = tb;
    }
    __syncthreads();
    if (t < NTY) {
        int run = hdr[8 + t];
        for (int b = 0; b < NPB; ++b) {
            cursor[t * NPB + b] = run;
            run += counts[t * NPB + b];
        }
    }
}

__global__ void scatter_k(const int* __restrict__ elems, int n, int chunk,
                          const int* __restrict__ cursor, int* __restrict__ sorted) {
    __shared__ int cur[NTY];
    if (threadIdx.x < NTY) cur[threadIdx.x] = cursor[threadIdx.x * NPB + blockIdx.x];
    __syncthreads();
    const int start = blockIdx.x * chunk;
    const int end   = min(start + chunk, n);
    for (int i = start + threadIdx.x; i < end; i += blockDim.x) {
        int ty  = elems[i];
        int pos = atomicAdd(&cur[ty], 1);   // LDS atomic: block-local
        sorted[pos] = i;
    }
}

// Pre-swizzle W1,W2 (fp32 [t][din][dout]) into bf16 MFMA-frag order:
// frag(t,tile,ks): 64 lanes x 16B contiguous; lane l elem j =
//   W[t][ks*32 + (l>>4)*8 + j][tile*16 + (l&15)]
__global__ void wconv_k(const float* __restrict__ W1, const float* __restrict__ W2,
                        unsigned short* __restrict__ w1s, unsigned short* __restrict__ w2s) {
    int gid  = blockIdx.x * blockDim.x + threadIdx.x;   // 0..65535
    int lane = gid & 63;
    int ks   = (gid >> 6) & 7;
    int tile = (gid >> 9) & 15;
    int t    = (gid >> 13) & 3;
    int layer = gid >> 15;
    const float* W = layer ? W2 : W1;
    unsigned short* o = layer ? w2s : w1s;
    int dbase = ks * 32 + ((lane >> 4) << 3);
    int col   = tile * 16 + (lane & 15);
    unsigned short v[8];
#pragma unroll
    for (int j = 0; j < 8; ++j)
        v[j] = f2bf(W[(size_t)t * 65536 + (size_t)(dbase + j) * 256 + col]);
    unsigned short* dst = o + ((size_t)(t * 16 + tile) * 8 + ks) * 512 + lane * 8;
    *(short8*)dst = *(short8*)v;
}

// ---------------------------------------------------------------------------
// Main fused MLP kernel: one block = 64 atoms of one type, 4 waves.
// LDS: 32 KB buf (x hi/lo per 128-dim chunk; reused as plain-bf16 h1),
// + biases + partials = ~35 KB -> 4 blocks/CU.
// ---------------------------------------------------------------------------
__global__ __launch_bounds__(256, 4) void mlp_k(
    const float* __restrict__ desc,
    const float* __restrict__ b1g,
    const float* __restrict__ b2g,
    const float* __restrict__ W3,
    const float* __restrict__ b3,
    const int* __restrict__ hdr,
    const int* __restrict__ sorted,
    const unsigned short* __restrict__ w1s,
    const unsigned short* __restrict__ w2s,
    float* __restrict__ out)
{
    __shared__ __align__(16) char buf[32768];   // x-chunk hi[0,16K) lo[16K,32K); later h1 [64][512B]
    __shared__ float biasLds[512];              // b1 | b2 for this type
    __shared__ float part[4][64];

    const int tid  = threadIdx.x;
    const int lane = tid & 63;
    const int w    = tid >> 6;

    const int total = hdr[16];
    const int b = blockIdx.x;
    if (b >= total) return;

    int t = 3;
    if      (b < hdr[13]) t = 0;
    else if (b < hdr[14]) t = 1;
    else if (b < hdr[15]) t = 2;
    const int tloc   = b - hdr[12 + t];
    const int cnt    = hdr[t];
    const int base   = hdr[8 + t];
    const int astart = tloc * 64;

    biasLds[tid]       = b1g[t * 256 + tid];
    biasLds[256 + tid] = b2g[t * 256 + tid];

    // staging identity (4 threads per atom slot)
    const int slot = tid >> 2;
    const int q4   = tid & 3;
    const int g    = astart + slot;
    const int idx  = (g < cnt) ? sorted[base + g] : -1;
    const float4* xrow = (const float4*)(desc + (size_t)(idx < 0 ? 0 : idx) * 256);

    const unsigned short* w1t = w1s + (size_t)t * (16 * 8 * 512);
    const unsigned short* w2t = w2s + (size_t)t * (16 * 8 * 512);

    // ---- layer 1 over two 128-dim K-chunks; acc[q][nt] persists across chunks
    f32x4 acc[4][4];
#pragma unroll
    for (int q = 0; q < 4; ++q)
#pragma unroll
        for (int nt = 0; nt < 4; ++nt)
            acc[q][nt] = (f32x4){0.f, 0.f, 0.f, 0.f};

#pragma unroll
    for (int c = 0; c < 2; ++c) {
        // stage chunk c: dims [c*128, c*128+128), bf16 hi/lo, swizzled
        {
            char* hi = buf;
            char* lo = buf + 16384;
#pragma unroll
            for (int i = 0; i < 8; ++i) {
                const int f = q4 + i * 4;            // float4 idx within chunk, 0..31
                float4 v;
                if (idx >= 0) v = xrow[c * 32 + f];
                else          v = make_float4(0.f, 0.f, 0.f, 0.f);
                unsigned short h4[4], l4[4];
                float xs[4] = {v.x, v.y, v.z, v.w};
#pragma unroll
                for (int r = 0; r < 4; ++r) {
                    h4[r] = f2bf(xs[r]);
                    l4[r] = f2bf(xs[r] - bf2f(h4[r]));
                }
                const int off = slot * 256 + ((f * 8) ^ ((slot & 7) << 4));
                *(ushort4*)(hi + off) = *(ushort4*)h4;
                *(ushort4*)(lo + off) = *(ushort4*)l4;
            }
        }
        __syncthreads();   // chunk staged

        const char* hi = buf;
        const char* lo = buf + 16384;
#pragma unroll
        for (int ksl = 0; ksl < 4; ++ksl) {
            const int ks = c * 4 + ksl;
            short8 af[4];
#pragma unroll
            for (int q = 0; q < 4; ++q)
                af[q] = *(const short8*)(w1t + ((size_t)((w * 4 + q) * 8 + ks)) * 512 + lane * 8);
            short8 bh[4], bl[4];
            const int colb = ksl * 64 + ((lane >> 4) << 4);
#pragma unroll
            for (int nt = 0; nt < 4; ++nt) {
                const int row = nt * 16 + (lane & 15);
                const int off = row * 256 + (colb ^ ((row & 7) << 4));
                bh[nt] = *(const short8*)(hi + off);
                bl[nt] = *(const short8*)(lo + off);
            }
#pragma unroll
            for (int q = 0; q < 4; ++q)
#pragma unroll
                for (int nt = 0; nt < 4; ++nt) {
                    acc[q][nt] = __builtin_amdgcn_mfma_f32_16x16x32_bf16(af[q], bh[nt], acc[q][nt], 0, 0, 0);
                    acc[q][nt] = __builtin_amdgcn_mfma_f32_16x16x32_bf16(af[q], bl[nt], acc[q][nt], 0, 0, 0);
                }
        }
        __syncthreads();   // chunk fully consumed (buffer free for reuse)
    }

    // ---- bias + tanh, write h1 (plain bf16) into buf as [atom][h] (512B rows)
#pragma unroll
    for (int q = 0; q < 4; ++q) {
        const int h0 = (w * 4 + q) * 16 + ((lane >> 4) << 2);
#pragma unroll
        for (int nt = 0; nt < 4; ++nt) {
            const int atom = nt * 16 + (lane & 15);
            unsigned short h4[4];
#pragma unroll
            for (int r = 0; r < 4; ++r)
                h4[r] = f2bf(fast_tanh(acc[q][nt][r] + biasLds[h0 + r]));
            const int off = atom * 512 + ((h0 * 2) ^ ((atom & 7) << 4));
            *(ushort4*)(buf + off) = *(ushort4*)h4;
        }
    }
    __syncthreads();   // h1 fully written

    // ---- layer 2: C[atom][kout] = h1(A) * W2t(B); wave owns kout-tiles w*4..
    f32x4 acc2[4][4];
#pragma unroll
    for (int mt = 0; mt < 4; ++mt)
#pragma unroll
        for (int q = 0; q < 4; ++q)
            acc2[mt][q] = (f32x4){0.f, 0.f, 0.f, 0.f};

#pragma unroll
    for (int ks = 0; ks < 8; ++ks) {
        short8 bw[4];
#pragma unroll
        for (int q = 0; q < 4; ++q)
            bw[q] = *(const short8*)(w2t + ((size_t)((w * 4 + q) * 8 + ks)) * 512 + lane * 8);
        short8 ah[4];
        const int colb = ks * 64 + ((lane >> 4) << 4);
#pragma unroll
        for (int mt = 0; mt < 4; ++mt) {
            const int row = mt * 16 + (lane & 15);
            const int off = row * 512 + (colb ^ ((row & 7) << 4));
            ah[mt] = *(const short8*)(buf + off);
        }
#pragma unroll
        for (int mt = 0; mt < 4; ++mt)
#pragma unroll
            for (int q = 0; q < 4; ++q)
                acc2[mt][q] = __builtin_amdgcn_mfma_f32_16x16x32_bf16(ah[mt], bw[q], acc2[mt][q], 0, 0, 0);
    }

    // ---- layer 3: fp32 dot with W3 over this wave's 64 kout columns
    float psum[4][4];
#pragma unroll
    for (int mt = 0; mt < 4; ++mt)
#pragma unroll
        for (int r = 0; r < 4; ++r)
            psum[mt][r] = 0.f;

#pragma unroll
    for (int q = 0; q < 4; ++q) {
        const int kout = (w * 4 + q) * 16 + (lane & 15);
        const float w3v = W3[t * 256 + kout];
        const float b2v = biasLds[256 + kout];
#pragma unroll
        for (int mt = 0; mt < 4; ++mt)
#pragma unroll
            for (int r = 0; r < 4; ++r)
                psum[mt][r] += fast_tanh(acc2[mt][q][r] + b2v) * w3v;
    }
#pragma unroll
    for (int m = 1; m <= 8; m <<= 1)
#pragma unroll
        for (int mt = 0; mt < 4; ++mt)
#pragma unroll
            for (int r = 0; r < 4; ++r)
                psum[mt][r] += __shfl_xor(psum[mt][r], m, 64);

    if ((lane & 15) == 0) {
        const int gq = lane >> 4;
#pragma unroll
        for (int mt = 0; mt < 4; ++mt)
#pragma unroll
            for (int r = 0; r < 4; ++r)
                part[w][mt * 16 + gq * 4 + r] = psum[mt][r];
    }
    __syncthreads();

    if (tid < 64) {
        const int gg = astart + tid;
        if (gg < cnt) {
            float v = part[0][tid] + part[1][tid] + part[2][tid] + part[3][tid] + b3[t];
            out[sorted[base + gg]] = v;
        }
    }
}

extern "C" void kernel_launch(void* const* d_in, const int* in_sizes, int n_in,
                              void* d_out, int out_size, void* d_ws, size_t ws_size,
                              hipStream_t stream) {
    const float* desc = (const float*)d_in[0];
    const int*   elems = (const int*)d_in[1];
    const float* W1 = (const float*)d_in[2];
    const float* b1 = (const float*)d_in[3];
    const float* W2 = (const float*)d_in[4];
    const float* b2 = (const float*)d_in[5];
    const float* W3 = (const float*)d_in[6];
    const float* b3 = (const float*)d_in[7];
    float* out = (float*)d_out;
    const int n = in_sizes[1];   // N_ATOMS

    char* ws = (char*)d_ws;
    int* hdr    = (int*)ws;                       // 32 ints
    int* counts = (int*)(ws + 128);               // 4*NPB ints
    int* cursor = (int*)(ws + 128 + 4 * NPB * 4); // 4*NPB ints
    int* sorted = (int*)(ws + 128 + 8 * NPB * 4);
    unsigned short* w1s = (unsigned short*)((char*)sorted + (size_t)n * 4);
    unsigned short* w2s = w1s + (size_t)4 * 16 * 8 * 512;

    const int chunk = (n + NPB - 1) / NPB;

    count_k<<<NPB, 256, 0, stream>>>(elems, n, chunk, counts);
    prefix_k<<<1, 64, 0, stream>>>(counts, cursor, hdr);
    scatter_k<<<NPB, 256, 0, stream>>>(elems, n, chunk, cursor, sorted);
    wconv_k<<<256, 256, 0, stream>>>(W1, W2, w1s, w2s);

    const int maxtiles = (n >> 6) + 4;
    mlp_k<<<maxtiles, 256, 0, stream>>>(desc, b1, b2, W3, b3,
                                        hdr, sorted, w1s, w2s, out);
}

// Round 7
// 113.018 us; speedup vs baseline: 1.2046x; 1.2046x over previous
//
#include <hip/hip_runtime.h>
#include <stdint.h>

// ---------------------------------------------------------------------------
// Per-type MLP dispatch (ElemwiseModels): out[n] = MLP_{elems[n]}(desc[n])
//   L1: h1 = tanh(x @ W1[t] + b1[t])     x:256 -> 256
//   L2: h2 = tanh(h1 @ W2[t] + b2[t])    256 -> 256
//   L3: out = h2 . W3[t] + b3[t]         256 -> 1
// Strategy: counting-sort partition by type; 64-atom tiles; bf16 MFMA.
// x: bf16 hi/lo split staged ONCE (64 KB LDS, r5 structure — r6's chunking
// regressed by serializing load latency). h1: plain bf16 (r6-validated,
// absmax unchanged) -> L2 is hi-only: 128 fewer MFMAs + half the ep1 VALU.
// ---------------------------------------------------------------------------

typedef __attribute__((ext_vector_type(8))) short short8;   // 8 x bf16 frag
typedef __attribute__((ext_vector_type(4))) float f32x4;    // MFMA acc

#define NPB 256          // partition blocks
#define NTY 4            // types

__device__ __forceinline__ unsigned short f2bf(float f) {
    union { float f; uint32_t u; } v; v.f = f;
    uint32_t u = v.u;
    uint32_t r = (u + 0x7FFFu + ((u >> 16) & 1u)) >> 16;   // RN-even
    return (unsigned short)r;
}
__device__ __forceinline__ float bf2f(unsigned short h) {
    union { uint32_t u; float f; } v; v.u = ((uint32_t)h) << 16;
    return v.f;
}
__device__ __forceinline__ float fast_tanh(float x) {
    x = fminf(fmaxf(x, -10.0f), 10.0f);
    float e = __expf(2.0f * x);
    return (e - 1.0f) * __builtin_amdgcn_rcpf(e + 1.0f);
}

// ---------------- ws layout -------------------------------------------------
// hdr   (32 ints @ 0):      [0..3] counts, [8..11] base, [12..15] tilebase, [16] total tiles
// counts(4*NPB ints @128):  counts[t*NPB + b]
// cursor(4*NPB ints):       cursor[t*NPB + b]
// sorted(n ints)
// w1s / w2s (bf16) after sorted
// ---------------------------------------------------------------------------

__global__ void count_k(const int* __restrict__ elems, int n, int chunk,
                        int* __restrict__ counts) {
    __shared__ int h[NTY];
    if (threadIdx.x < NTY) h[threadIdx.x] = 0;
    __syncthreads();
    const int start = blockIdx.x * chunk;
    const int end   = min(start + chunk, n);
    for (int i = start + threadIdx.x; i < end; i += blockDim.x)
        atomicAdd(&h[elems[i]], 1);
    __syncthreads();
    if (threadIdx.x < NTY) counts[threadIdx.x * NPB + blockIdx.x] = h[threadIdx.x];
}

__global__ void prefix_k(const int* __restrict__ counts,
                         int* __restrict__ cursor, int* __restrict__ hdr) {
    __shared__ int tot[NTY];
    const int t = threadIdx.x;
    if (t < NTY) {
        int s = 0;
        for (int b = 0; b < NPB; ++b) s += counts[t * NPB + b];
        tot[t] = s;
    }
    __syncthreads();
    if (t == 0) {
        int b = 0, tb = 0;
        for (int ty = 0; ty < NTY; ++ty) {
            hdr[ty]      = tot[ty];
            hdr[8 + ty]  = b;
            hdr[12 + ty] = tb;
            b  += tot[ty];
            tb += (tot[ty] + 63) >> 6;
        }
        hdr[16] = tb;
    }
    __syncthreads();
    if (t < NTY) {
        int run = hdr[8 + t];
        for (int b = 0; b < NPB; ++b) {
            cursor[t * NPB + b] = run;
            run += counts[t * NPB + b];
        }
    }
}

__global__ void scatter_k(const int* __restrict__ elems, int n, int chunk,
                          const int* __restrict__ cursor, int* __restrict__ sorted) {
    __shared__ int cur[NTY];
    if (threadIdx.x < NTY) cur[threadIdx.x] = cursor[threadIdx.x * NPB + blockIdx.x];
    __syncthreads();
    const int start = blockIdx.x * chunk;
    const int end   = min(start + chunk, n);
    for (int i = start + threadIdx.x; i < end; i += blockDim.x) {
        int ty  = elems[i];
        int pos = atomicAdd(&cur[ty], 1);   // LDS atomic: block-local
        sorted[pos] = i;
    }
}

// Pre-swizzle W1,W2 (fp32 [t][din][dout]) into bf16 MFMA-frag order:
// frag(t,tile,ks): 64 lanes x 16B contiguous; lane l elem j =
//   W[t][ks*32 + (l>>4)*8 + j][tile*16 + (l&15)]
__global__ void wconv_k(const float* __restrict__ W1, const float* __restrict__ W2,
                        unsigned short* __restrict__ w1s, unsigned short* __restrict__ w2s) {
    int gid  = blockIdx.x * blockDim.x + threadIdx.x;   // 0..65535
    int lane = gid & 63;
    int ks   = (gid >> 6) & 7;
    int tile = (gid >> 9) & 15;
    int t    = (gid >> 13) & 3;
    int layer = gid >> 15;
    const float* W = layer ? W2 : W1;
    unsigned short* o = layer ? w2s : w1s;
    int dbase = ks * 32 + ((lane >> 4) << 3);
    int col   = tile * 16 + (lane & 15);
    unsigned short v[8];
#pragma unroll
    for (int j = 0; j < 8; ++j)
        v[j] = f2bf(W[(size_t)t * 65536 + (size_t)(dbase + j) * 256 + col]);
    unsigned short* dst = o + ((size_t)(t * 16 + tile) * 8 + ks) * 512 + lane * 8;
    *(short8*)dst = *(short8*)v;
}

// ---------------------------------------------------------------------------
// Main fused MLP kernel: one block = 64 atoms of one type, 4 waves.
// LDS buf (64 KB) holds x (bf16 hi/lo, [atom][d], XOR-swizzled); the hi
// half is then reused for plain-bf16 h1 between the two MFMA layers.
// ---------------------------------------------------------------------------
__global__ __launch_bounds__(256, 2) void mlp_k(
    const float* __restrict__ desc,
    const float* __restrict__ b1g,
    const float* __restrict__ b2g,
    const float* __restrict__ W3,
    const float* __restrict__ b3,
    const int* __restrict__ hdr,
    const int* __restrict__ sorted,
    const unsigned short* __restrict__ w1s,
    const unsigned short* __restrict__ w2s,
    float* __restrict__ out)
{
    __shared__ __align__(16) char buf[65536];   // x: hi[0,32K) lo[32K,64K); h1 reuses [0,32K)
    __shared__ float biasLds[512];              // b1 | b2 for this type
    __shared__ float part[4][64];

    const int tid  = threadIdx.x;
    const int lane = tid & 63;
    const int w    = tid >> 6;

    const int total = hdr[16];
    const int b = blockIdx.x;
    if (b >= total) return;

    int t = 3;
    if      (b < hdr[13]) t = 0;
    else if (b < hdr[14]) t = 1;
    else if (b < hdr[15]) t = 2;
    const int tloc   = b - hdr[12 + t];
    const int cnt    = hdr[t];
    const int base   = hdr[8 + t];
    const int astart = tloc * 64;

    biasLds[tid]       = b1g[t * 256 + tid];
    biasLds[256 + tid] = b2g[t * 256 + tid];

    // ---- stage descriptors: 4 threads per atom slot, bf16 hi/lo, swizzled
    {
        const int slot = tid >> 2;
        const int q    = tid & 3;
        const int g    = astart + slot;
        const int idx  = (g < cnt) ? sorted[base + g] : -1;
        const float4* row = (const float4*)(desc + (size_t)(idx < 0 ? 0 : idx) * 256);
        char* hi = buf;
        char* lo = buf + 32768;
#pragma unroll
        for (int i = 0; i < 16; ++i) {
            const int f = q + i * 4;         // float4 index within row
            float4 v;
            if (idx >= 0) v = row[f];
            else          v = make_float4(0.f, 0.f, 0.f, 0.f);
            unsigned short h4[4], l4[4];
            float xs[4] = {v.x, v.y, v.z, v.w};
#pragma unroll
            for (int r = 0; r < 4; ++r) {
                h4[r] = f2bf(xs[r]);
                l4[r] = f2bf(xs[r] - bf2f(h4[r]));
            }
            const int off = slot * 512 + ((f * 8) ^ ((slot & 7) << 4));
            *(ushort4*)(hi + off) = *(ushort4*)h4;
            *(ushort4*)(lo + off) = *(ushort4*)l4;
        }
    }
    __syncthreads();

    const char* hi = buf;
    const char* lo = buf + 32768;
    const unsigned short* w1t = w1s + (size_t)t * (16 * 8 * 512);
    const unsigned short* w2t = w2s + (size_t)t * (16 * 8 * 512);

    // ---- layer 1: C[h][atom] = W1t(A) * x(B);  wave owns h-tiles w*4..w*4+3
    f32x4 acc[4][4];
#pragma unroll
    for (int q = 0; q < 4; ++q)
#pragma unroll
        for (int nt = 0; nt < 4; ++nt)
            acc[q][nt] = (f32x4){0.f, 0.f, 0.f, 0.f};

#pragma unroll
    for (int ks = 0; ks < 8; ++ks) {
        short8 af[4];
#pragma unroll
        for (int q = 0; q < 4; ++q)
            af[q] = *(const short8*)(w1t + ((size_t)((w * 4 + q) * 8 + ks)) * 512 + lane * 8);
        short8 bh[4], bl[4];
        const int colb = ks * 64 + ((lane >> 4) << 4);
#pragma unroll
        for (int nt = 0; nt < 4; ++nt) {
            const int row = nt * 16 + (lane & 15);
            const int off = row * 512 + (colb ^ ((row & 7) << 4));
            bh[nt] = *(const short8*)(hi + off);
            bl[nt] = *(const short8*)(lo + off);
        }
#pragma unroll
        for (int q = 0; q < 4; ++q)
#pragma unroll
            for (int nt = 0; nt < 4; ++nt) {
                acc[q][nt] = __builtin_amdgcn_mfma_f32_16x16x32_bf16(af[q], bh[nt], acc[q][nt], 0, 0, 0);
                acc[q][nt] = __builtin_amdgcn_mfma_f32_16x16x32_bf16(af[q], bl[nt], acc[q][nt], 0, 0, 0);
            }
    }
    __syncthreads();   // everyone done reading x from buf

    // ---- bias + tanh, write h1 (plain bf16) into buf[0,32K) as [atom][h]
    {
#pragma unroll
        for (int q = 0; q < 4; ++q) {
            const int h0 = (w * 4 + q) * 16 + ((lane >> 4) << 2);
#pragma unroll
            for (int nt = 0; nt < 4; ++nt) {
                const int atom = nt * 16 + (lane & 15);
                unsigned short h4[4];
#pragma unroll
                for (int r = 0; r < 4; ++r)
                    h4[r] = f2bf(fast_tanh(acc[q][nt][r] + biasLds[h0 + r]));
                const int off = atom * 512 + ((h0 * 2) ^ ((atom & 7) << 4));
                *(ushort4*)(buf + off) = *(ushort4*)h4;
            }
        }
    }
    __syncthreads();   // h1 fully written

    // ---- layer 2 (hi-only): C[atom][kout] = h1(A) * W2t(B)
    f32x4 acc2[4][4];
#pragma unroll
    for (int mt = 0; mt < 4; ++mt)
#pragma unroll
        for (int q = 0; q < 4; ++q)
            acc2[mt][q] = (f32x4){0.f, 0.f, 0.f, 0.f};

#pragma unroll
    for (int ks = 0; ks < 8; ++ks) {
        short8 bw[4];
#pragma unroll
        for (int q = 0; q < 4; ++q)
            bw[q] = *(const short8*)(w2t + ((size_t)((w * 4 + q) * 8 + ks)) * 512 + lane * 8);
        short8 ah[4];
        const int colb = ks * 64 + ((lane >> 4) << 4);
#pragma unroll
        for (int mt = 0; mt < 4; ++mt) {
            const int row = mt * 16 + (lane & 15);
            const int off = row * 512 + (colb ^ ((row & 7) << 4));
            ah[mt] = *(const short8*)(buf + off);
        }
#pragma unroll
        for (int mt = 0; mt < 4; ++mt)
#pragma unroll
            for (int q = 0; q < 4; ++q)
                acc2[mt][q] = __builtin_amdgcn_mfma_f32_16x16x32_bf16(ah[mt], bw[q], acc2[mt][q], 0, 0, 0);
    }

    // ---- layer 3: fp32 dot with W3 over this wave's 64 kout columns
    float psum[4][4];
#pragma unroll
    for (int mt = 0; mt < 4; ++mt)
#pragma unroll
        for (int r = 0; r < 4; ++r)
            psum[mt][r] = 0.f;

#pragma unroll
    for (int q = 0; q < 4; ++q) {
        const int kout = (w * 4 + q) * 16 + (lane & 15);
        const float w3v = W3[t * 256 + kout];
        const float b2v = biasLds[256 + kout];
#pragma unroll
        for (int mt = 0; mt < 4; ++mt)
#pragma unroll
            for (int r = 0; r < 4; ++r)
                psum[mt][r] += fast_tanh(acc2[mt][q][r] + b2v) * w3v;
    }
#pragma unroll
    for (int m = 1; m <= 8; m <<= 1)
#pragma unroll
        for (int mt = 0; mt < 4; ++mt)
#pragma unroll
            for (int r = 0; r < 4; ++r)
                psum[mt][r] += __shfl_xor(psum[mt][r], m, 64);

    if ((lane & 15) == 0) {
        const int gq = lane >> 4;
#pragma unroll
        for (int mt = 0; mt < 4; ++mt)
#pragma unroll
            for (int r = 0; r < 4; ++r)
                part[w][mt * 16 + gq * 4 + r] = psum[mt][r];
    }
    __syncthreads();

    if (tid < 64) {
        const int gg = astart + tid;
        if (gg < cnt) {
            float v = part[0][tid] + part[1][tid] + part[2][tid] + part[3][tid] + b3[t];
            out[sorted[base + gg]] = v;
        }
    }
}

extern "C" void kernel_launch(void* const* d_in, const int* in_sizes, int n_in,
                              void* d_out, int out_size, void* d_ws, size_t ws_size,
                              hipStream_t stream) {
    const float* desc = (const float*)d_in[0];
    const int*   elems = (const int*)d_in[1];
    const float* W1 = (const float*)d_in[2];
    const float* b1 = (const float*)d_in[3];
    const float* W2 = (const float*)d_in[4];
    const float* b2 = (const float*)d_in[5];
    const float* W3 = (const float*)d_in[6];
    const float* b3 = (const float*)d_in[7];
    float* out = (float*)d_out;
    const int n = in_sizes[1];   // N_ATOMS

    char* ws = (char*)d_ws;
    int* hdr    = (int*)ws;                       // 32 ints
    int* counts = (int*)(ws + 128);               // 4*NPB ints
    int* cursor = (int*)(ws + 128 + 4 * NPB * 4); // 4*NPB ints
    int* sorted = (int*)(ws + 128 + 8 * NPB * 4);
    unsigned short* w1s = (unsigned short*)((char*)sorted + (size_t)n * 4);
    unsigned short* w2s = w1s + (size_t)4 * 16 * 8 * 512;

    const int chunk = (n + NPB - 1) / NPB;

    count_k<<<NPB, 256, 0, stream>>>(elems, n, chunk, counts);
    prefix_k<<<1, 64, 0, stream>>>(counts, cursor, hdr);
    scatter_k<<<NPB, 256, 0, stream>>>(elems, n, chunk, cursor, sorted);
    wconv_k<<<256, 256, 0, stream>>>(W1, W2, w1s, w2s);

    const int maxtiles = (n >> 6) + 4;
    mlp_k<<<maxtiles, 256, 0, stream>>>(desc, b1, b2, W3, b3,
                                        hdr, sorted, w1s, w2s, out);
}